// Round 9
// baseline (402.924 us; speedup 1.0000x reference)
//
#include <hip/hip_runtime.h>
#include <math.h>

#define N_ROWS   65536
#define DIM      256
#define KCODES   1024
#define Q_SIZE   (N_ROWS * DIM)          // 16777216
#define OUT_LOSS Q_SIZE
#define OUT_PERP (Q_SIZE + 1)
#define OUT_IDX  (Q_SIZE + 2)

// flag threshold in scaled-score units (s' = 2^20 * d2-units). Same as r8 (passed).
#define TAUP 200.0f

// ws layout (bytes)
#define WS_LOSS   0        // double
#define WS_RCNT   8        // int
#define WS_E2     16       // float[1024]  original units
#define WS_E2P    4112     // float[1024]  scaled by 2^20
#define WS_COUNTS 8208     // int[1024]
#define WS_IDX    12304    // int[65536]
#define WS_RLIST  274448   // int[65536]
#define WS_ET     536592   // float[262144]   E^T fp32 (refine)
#define WS_P      1585168  // _Float16[262144] packed f16(1024*E) per-wave linear

typedef _Float16 half8 __attribute__((ext_vector_type(8)));
typedef _Float16 half4 __attribute__((ext_vector_type(4)));
typedef float    f32x4 __attribute__((ext_vector_type(4)));

#define ROWB 528    // LDS bytes per row: 512 (xh) + 16 pad
#define RPB  64     // rows per block

// ---------------------------------------------------------------------------
// prep: e2, e2p, Et (fp32 transpose, refine), packed P; zero accums.
// P layout (r9): P[q][cb][kk][nt][lane][8 halfs] — the exact per-wave B-frag
// stream order, so each k_main B-load is one contiguous 1KB/wave read.
//   code = q*256 + cb*64 + nt*16 + (lane&15), d = (lane>>4)*8 + kk*32 + j
// grid 1024 x 256
__global__ void k_prep(const float* __restrict__ E, float* __restrict__ e2,
                       float* __restrict__ e2p, float* __restrict__ Et,
                       _Float16* __restrict__ P,
                       int* __restrict__ counts, double* __restrict__ loss,
                       int* __restrict__ rcnt) {
    int b = blockIdx.x, t = threadIdx.x;
    __shared__ double red[256];
    float v = E[b * DIM + t];
    red[t] = (double)v * (double)v;

    {   // packed B-stream write
        int o   = b * 256 + t;
        int j    = o & 7;
        int lane = (o >> 3) & 63;
        int nt   = (o >> 9) & 3;
        int kk   = (o >> 11) & 7;
        int cbq  = o >> 14;            // 0..15
        int q = cbq >> 2, cb = cbq & 3;
        int code = q * 256 + cb * 64 + nt * 16 + (lane & 15);
        int d    = (lane >> 4) * 8 + kk * 32 + j;
        P[o] = (_Float16)(E[code * DIM + d] * 1024.0f);   // exact scaling, RN
    }

    __syncthreads();
    for (int s = 128; s > 0; s >>= 1) {
        if (t < s) red[t] += red[t + s];
        __syncthreads();
    }
    if (t == 0) { e2[b] = (float)red[0]; e2p[b] = (float)(red[0] * 1048576.0); }

    int o = b * 256 + t;
    int d = o >> 10, k = o & 1023;
    Et[o] = E[k * DIM + d];

    if (b < 4) counts[b * 256 + t] = 0;
    if (b == 0 && t == 0) { *loss = 0.0; *rcnt = 0; }
}

// ---------------------------------------------------------------------------
// main: MFMA ranking, single f16 product xh*Eh (identical numerics to r8).
// r9 change: packed-linear B stream + explicit 2-deep prefetch pipeline over a
// flattened 32-step (cb,kk) loop — r8 showed B-loads executing as a serial
// ~450cyc/load L2 chain (kernel time ∝ load count across r5/r7/r8).
// OCCUPANCY NOTE (r4-r7): never use a min-waves launch bound here (spills).
// grid 1024 x 256
__launch_bounds__(256)
__global__ void k_main(const float* __restrict__ X, const _Float16* __restrict__ P,
                       const float* __restrict__ e2p,
                       int* __restrict__ idx_ws, int* __restrict__ rlist,
                       int* __restrict__ rcnt) {
    __shared__ __align__(16) char sA[RPB * ROWB];   // 33792 B
    const int tid  = threadIdx.x;
    const int wid  = tid >> 6;
    const int lane = tid & 63;
    const int c16  = lane & 15;
    const int kg   = lane >> 4;
    const int rb   = blockIdx.x * RPB;

    // ---- stage X -> f16 (hi only) in LDS (coalesced float4 reads) ----
    {
        const float4* Xg = (const float4*)(X + (size_t)rb * DIM);
        #pragma unroll
        for (int it = 0; it < 16; ++it) {
            int f = it * 256 + tid;
            int row = f >> 6, d4 = f & 63;
            float4 v = Xg[(size_t)row * 64 + d4];
            half4 hh = {(_Float16)v.x, (_Float16)v.y, (_Float16)v.z, (_Float16)v.w};
            *(half4*)(sA + row * ROWB + d4 * 8) = hh;
        }
    }
    __syncthreads();

    int Abase[4];
    #pragma unroll
    for (int mt = 0; mt < 4; ++mt) Abase[mt] = (mt * 16 + c16) * ROWB + kg * 16;

    float tb1[16], tb2[16];
    int   ti1[16];
    #pragma unroll
    for (int i = 0; i < 16; ++i) { tb1[i] = 3.4e38f; tb2[i] = 3.4e38f; ti1[i] = 0; }

    const int cw = wid * 256;
    // per-wave contiguous B stream: 128 KB per quarter, lane offset 16B
    const char* bpB = (const char*)P + (size_t)wid * 131072 + (size_t)lane * 16;
#define BLOAD(s, nt) (*(const half8*)(bpB + ((s) * 4 + (nt)) * 1024))

    half8 bA[4], bB[4], bC[4];
    #pragma unroll
    for (int nt = 0; nt < 4; ++nt) bA[nt] = BLOAD(0, nt);
    #pragma unroll
    for (int nt = 0; nt < 4; ++nt) bB[nt] = BLOAD(1, nt);

    f32x4 acc[4][4];

    #pragma unroll
    for (int s = 0; s < 32; ++s) {
        const int cb = s >> 3, kk = s & 7;
        if (kk == 0) {
            #pragma unroll
            for (int mt = 0; mt < 4; ++mt)
                #pragma unroll
                for (int nt = 0; nt < 4; ++nt) acc[mt][nt] = 0.0f;
        }
        if (s < 30) {
            #pragma unroll
            for (int nt = 0; nt < 4; ++nt) bC[nt] = BLOAD(s + 2, nt);
        }
        half8 ah[4];
        #pragma unroll
        for (int mt = 0; mt < 4; ++mt)
            ah[mt] = *(const half8*)(sA + Abase[mt] + kk * 64);
        #pragma unroll
        for (int mt = 0; mt < 4; ++mt) {
            acc[mt][0] = __builtin_amdgcn_mfma_f32_16x16x32_f16(ah[mt], bA[0], acc[mt][0], 0, 0, 0);
            acc[mt][1] = __builtin_amdgcn_mfma_f32_16x16x32_f16(ah[mt], bA[1], acc[mt][1], 0, 0, 0);
            acc[mt][2] = __builtin_amdgcn_mfma_f32_16x16x32_f16(ah[mt], bA[2], acc[mt][2], 0, 0, 0);
            acc[mt][3] = __builtin_amdgcn_mfma_f32_16x16x32_f16(ah[mt], bA[3], acc[mt][3], 0, 0, 0);
        }
        if (kk == 7) {
            // epilogue: s' = e2' - 2048*dot', sorted-insert top-2
            const int cbase = cw + cb * 64;
            const int c0 = cbase + c16;
            float e2v[4];
            #pragma unroll
            for (int nt = 0; nt < 4; ++nt) e2v[nt] = e2p[c0 + nt * 16];
            #pragma unroll
            for (int mt = 0; mt < 4; ++mt)
                #pragma unroll
                for (int nt = 0; nt < 4; ++nt) {
                    int code = cbase + nt * 16 + c16;
                    #pragma unroll
                    for (int r = 0; r < 4; ++r) {
                        float sc = fmaf(-2048.0f, acc[mt][nt][r], e2v[nt]);
                        int ix = mt * 4 + r;
                        float hi = fmaxf(tb1[ix], sc);
                        tb2[ix] = fminf(tb2[ix], hi);
                        bool lt = sc < tb1[ix];
                        tb1[ix] = lt ? sc : tb1[ix];
                        ti1[ix] = lt ? code : ti1[ix];
                    }
                }
        }
        #pragma unroll
        for (int nt = 0; nt < 4; ++nt) { bA[nt] = bB[nt]; bB[nt] = bC[nt]; }
    }
#undef BLOAD

    // ---- butterfly merge across the 16 col-lanes of each kg group ----
    #pragma unroll
    for (int ix = 0; ix < 16; ++ix) {
        float v1 = tb1[ix], v2 = tb2[ix];
        int   j1 = ti1[ix];
        #pragma unroll
        for (int m = 1; m < 16; m <<= 1) {
            float ov1 = __shfl_xor(v1, m, 64);
            int   oj1 = __shfl_xor(j1, m, 64);
            float ov2 = __shfl_xor(v2, m, 64);
            bool take = (ov1 < v1) || (ov1 == v1 && oj1 < j1);
            float losr = take ? v1 : ov1;
            v1 = take ? ov1 : v1;
            j1 = take ? oj1 : j1;
            v2 = fminf(fminf(v2, ov2), losr);
        }
        tb1[ix] = v1; tb2[ix] = v2; ti1[ix] = j1;
    }

    // ---- cross-wave merge via LDS (reuse sA) ----
    __syncthreads();
    float* mB1 = (float*)sA;            // [64][4]
    float* mB2 = (float*)(sA + 1024);   // [64][4]
    int*   mI1 = (int*)(sA + 2048);     // [64][4]
    #pragma unroll
    for (int ix = 0; ix < 16; ++ix) {
        if (c16 == ix) {
            int row = (ix >> 2) * 16 + kg * 4 + (ix & 3);
            mB1[row * 4 + wid] = tb1[ix];
            mB2[row * 4 + wid] = tb2[ix];
            mI1[row * 4 + wid] = ti1[ix];
        }
    }
    __syncthreads();
    if (tid < RPB) {
        float m1 = 3.4e38f, m2 = 3.4e38f;
        int mi = 0;
        #pragma unroll
        for (int w = 0; w < 4; ++w) {
            float v = mB1[tid * 4 + w];
            int  id = mI1[tid * 4 + w];
            float u = mB2[tid * 4 + w];
            bool take = (v < m1) || (v == m1 && id < mi);
            float losr = take ? m1 : v;
            m1 = take ? v : m1;
            mi = take ? id : mi;
            m2 = fminf(fminf(m2, u), losr);
        }
        int g = rb + tid;
        idx_ws[g] = mi;
        if (m2 - m1 < TAUP) {
            int slot = atomicAdd(rcnt, 1);
            rlist[slot] = g;
        }
    }
}

// ---------------------------------------------------------------------------
// refine: exact reference-fp32 replication, now 8 rows per Et sweep (r9):
// r8 read the full 1MB Et per flagged row (~2.5GB L2 ≈ 70µs); batching 8 rows
// cuts Et traffic 8x. Per-row fp64 accumulation order over d is UNCHANGED.
// grid 512 x 256
__global__ void k_refine(const float* __restrict__ X, const float* __restrict__ Et,
                         const float* __restrict__ e2,
                         const int* __restrict__ rlist, const int* __restrict__ rcnt,
                         int* __restrict__ idx_ws) {
    __shared__ float xs[8][256];
    __shared__ float sbv[8][256];
    __shared__ int   sbi[8][256];
    __shared__ float x2s[8];
    __shared__ int   rows[8];
    const int cnt = *rcnt;
    const int t = threadIdx.x;
    for (int base = blockIdx.x * 8; base < cnt; base += gridDim.x * 8) {
        __syncthreads();
        if (t < 8) {
            int e = base + t;
            rows[t] = rlist[e < cnt ? e : (cnt - 1)];
        }
        __syncthreads();
        // stage 8 rows of X
        #pragma unroll
        for (int i = 0; i < 2; ++i) {
            int idx = t + i * 256;          // 0..511 float4 slots
            int r = idx >> 6, c4 = idx & 63;
            ((float4*)xs[r])[c4] = ((const float4*)(X + (size_t)rows[r] * DIM))[c4];
        }
        __syncthreads();
        // x2_32 per row (fp64 serial over d, fl32)
        if (t < 8) {
            double s = 0.0;
            for (int d = 0; d < DIM; ++d) { double xv = (double)xs[t][d]; s += xv * xv; }
            x2s[t] = (float)s;
        }
        __syncthreads();

        // fp64 dots: thread t owns codes {t, t+256, t+512, t+768} for all 8 rows
        double a0[8], a1[8], a2[8], a3[8];
        #pragma unroll
        for (int r = 0; r < 8; ++r) { a0[r] = 0.0; a1[r] = 0.0; a2[r] = 0.0; a3[r] = 0.0; }
        for (int d = 0; d < DIM; ++d) {
            double e0 = (double)Et[d * KCODES + t];
            double e1 = (double)Et[d * KCODES + 256 + t];
            double e2d = (double)Et[d * KCODES + 512 + t];
            double e3 = (double)Et[d * KCODES + 768 + t];
            #pragma unroll
            for (int r = 0; r < 8; ++r) {
                double xv = (double)xs[r][d];
                a0[r] += xv * e0;
                a1[r] += xv * e1;
                a2[r] += xv * e2d;
                a3[r] += xv * e3;
            }
        }

        // per-thread best over its 4 codes, per row (fp32-replicated pipeline)
        const float eA = e2[t], eB = e2[256 + t], eC = e2[512 + t], eD = e2[768 + t];
        #pragma unroll
        for (int r = 0; r < 8; ++r) {
            float best = 3.4e38f; int bk = 0;
            float x2 = x2s[r];
            {
                float d2 = fmaf(-2.f, (float)a0[r], x2 + eA);
                if (d2 < best) { best = d2; bk = t; }
            }
            {
                float d2 = fmaf(-2.f, (float)a1[r], x2 + eB);
                if (d2 < best) { best = d2; bk = 256 + t; }
            }
            {
                float d2 = fmaf(-2.f, (float)a2[r], x2 + eC);
                if (d2 < best) { best = d2; bk = 512 + t; }
            }
            {
                float d2 = fmaf(-2.f, (float)a3[r], x2 + eD);
                if (d2 < best) { best = d2; bk = 768 + t; }
            }
            sbv[r][t] = best; sbi[r][t] = bk;
        }
        __syncthreads();
        // final reduce: wave w handles rows 2w, 2w+1
        {
            const int w = t >> 6, lane = t & 63;
            #pragma unroll
            for (int i = 0; i < 2; ++i) {
                int r = w * 2 + i;
                float v = sbv[r][lane];     int id = sbi[r][lane];
                #pragma unroll
                for (int c = 1; c < 4; ++c) {
                    float ov = sbv[r][lane + 64 * c]; int oi = sbi[r][lane + 64 * c];
                    if (ov < v || (ov == v && oi < id)) { v = ov; id = oi; }
                }
                #pragma unroll
                for (int m = 1; m < 64; m <<= 1) {
                    float ov = __shfl_xor(v, m, 64);
                    int   oi = __shfl_xor(id, m, 64);
                    if (ov < v || (ov == v && oi < id)) { v = ov; id = oi; }
                }
                if (lane == 0 && base + r < cnt) idx_ws[rows[r]] = id;
            }
        }
    }
}

// ---------------------------------------------------------------------------
// out: quantized rows, index output, loss, histogram. One fp64 atomic/block.
// grid 1024 x 256
__launch_bounds__(256)
__global__ void k_out(const float* __restrict__ X, const float* __restrict__ E,
                      const int* __restrict__ idx_ws, float* __restrict__ out,
                      int* __restrict__ counts, double* __restrict__ loss) {
    const int tid = threadIdx.x;
    const int w = tid >> 6, lane = tid & 63;
    const int rbase = blockIdx.x * 64;
    double ls = 0.0;
    #pragma unroll 4
    for (int it = 0; it < 16; ++it) {
        const int row = rbase + it * 4 + w;
        const int k = idx_ws[row];
        float4 q = ((const float4*)(E + (size_t)k * DIM))[lane];
        float4 x = ((const float4*)(X + (size_t)row * DIM))[lane];
        ((float4*)(out + (size_t)row * DIM))[lane] = q;
        double d0 = (double)q.x - (double)x.x;
        double d1 = (double)q.y - (double)x.y;
        double d2 = (double)q.z - (double)x.z;
        double d3 = (double)q.w - (double)x.w;
        ls += d0 * d0 + d1 * d1 + d2 * d2 + d3 * d3;
        if (lane == 0) {
            atomicAdd(&counts[k], 1);
            out[OUT_IDX + row] = (float)k;
        }
    }
    __shared__ double red[256];
    red[tid] = ls;
    __syncthreads();
    for (int s = 128; s > 0; s >>= 1) {
        if (tid < s) red[tid] += red[tid + s];
        __syncthreads();
    }
    if (tid == 0) atomicAdd(loss, red[0]);
}

// ---------------------------------------------------------------------------
// fin: scalars
__global__ void k_fin(const int* __restrict__ counts, const double* __restrict__ loss,
                      float* __restrict__ out) {
    int t = threadIdx.x;
    __shared__ double red[256];
    double h = 0.0;
    #pragma unroll
    for (int i = 0; i < 4; ++i) {
        double p = (double)counts[t + i * 256] / (double)N_ROWS;
        h += p * log(p + 1e-10);
    }
    red[t] = h;
    __syncthreads();
    for (int s = 128; s > 0; s >>= 1) {
        if (t < s) red[t] += red[t + s];
        __syncthreads();
    }
    if (t == 0) {
        out[OUT_PERP] = (float)exp(-red[0]);
        out[OUT_LOSS] = (float)((*loss) / (double)Q_SIZE * 1.25);
    }
}

// ---------------------------------------------------------------------------
extern "C" void kernel_launch(void* const* d_in, const int* in_sizes, int n_in,
                              void* d_out, int out_size, void* d_ws, size_t ws_size,
                              hipStream_t stream) {
    (void)in_sizes; (void)n_in; (void)out_size; (void)ws_size;
    const float* X = (const float*)d_in[0];
    const float* E = (const float*)d_in[1];
    float* out = (float*)d_out;
    char* ws = (char*)d_ws;

    double*    loss   = (double*)(ws + WS_LOSS);
    int*       rcnt   = (int*)(ws + WS_RCNT);
    float*     e2     = (float*)(ws + WS_E2);
    float*     e2p    = (float*)(ws + WS_E2P);
    int*       counts = (int*)(ws + WS_COUNTS);
    int*       idx_ws = (int*)(ws + WS_IDX);
    int*       rlist  = (int*)(ws + WS_RLIST);
    float*     Et     = (float*)(ws + WS_ET);
    _Float16*  Pp     = (_Float16*)(ws + WS_P);

    k_prep<<<1024, 256, 0, stream>>>(E, e2, e2p, Et, Pp, counts, loss, rcnt);
    k_main<<<N_ROWS / RPB, 256, 0, stream>>>(X, Pp, e2p, idx_ws, rlist, rcnt);
    k_refine<<<512, 256, 0, stream>>>(X, Et, e2, rlist, rcnt, idx_ws);
    k_out<<<1024, 256, 0, stream>>>(X, E, idx_ws, out, counts, loss);
    k_fin<<<1, 256, 0, stream>>>(counts, loss, out);
}

// Round 10
// 198.392 us; speedup vs baseline: 2.0310x; 2.0310x over previous
//
#include <hip/hip_runtime.h>
#include <math.h>

#define N_ROWS   65536
#define DIM      256
#define KCODES   1024
#define Q_SIZE   (N_ROWS * DIM)          // 16777216
#define OUT_LOSS Q_SIZE
#define OUT_PERP (Q_SIZE + 1)
#define OUT_IDX  (Q_SIZE + 2)

// flag threshold in scaled-score units (s' = 2^20 * d2-units). Same as r8 (passed).
#define TAUP 200.0f

// ws layout (bytes)
#define WS_LOSS   0        // double
#define WS_RCNT   8        // int
#define WS_E2     16       // float[1024]  original units
#define WS_E2P    4112     // float[1024]  scaled by 2^20
#define WS_COUNTS 8208     // int[1024]
#define WS_IDX    12304    // int[65536]
#define WS_RLIST  274448   // int[65536]
#define WS_ET     536592   // float[262144]   E^T fp32 (refine)
#define WS_P      1585168  // _Float16[262144] packed f16(1024*E) per-wave linear

typedef _Float16 half8 __attribute__((ext_vector_type(8)));
typedef _Float16 half4 __attribute__((ext_vector_type(4)));
typedef float    f32x4 __attribute__((ext_vector_type(4)));

#define ROWB 528    // LDS bytes per X row: 512 (xh) + 16 pad
#define RPB  64     // rows per block

// k_main LDS carve (single block): X 33792 | e2p 4096 | B dbuf 32768 = 70656 B
#define LDS_X  0
#define LDS_E2 33792
#define LDS_B  37888

// ---------------------------------------------------------------------------
// prep: e2, e2p, Et (fp32 transpose, refine), packed P; zero accums.
// P layout: P[q][cb][kk][nt][lane][8 halfs] — per-wave linear B-frag stream;
// each 1KB chunk is exactly lane-linear (lane*16B) => global_load_lds-ready.
// grid 1024 x 256
__global__ void k_prep(const float* __restrict__ E, float* __restrict__ e2,
                       float* __restrict__ e2p, float* __restrict__ Et,
                       _Float16* __restrict__ P,
                       int* __restrict__ counts, double* __restrict__ loss,
                       int* __restrict__ rcnt) {
    int b = blockIdx.x, t = threadIdx.x;
    __shared__ double red[256];
    float v = E[b * DIM + t];
    red[t] = (double)v * (double)v;

    {   // packed B-stream write
        int o   = b * 256 + t;
        int j    = o & 7;
        int lane = (o >> 3) & 63;
        int nt   = (o >> 9) & 3;
        int kk   = (o >> 11) & 7;
        int cbq  = o >> 14;            // 0..15
        int q = cbq >> 2, cb = cbq & 3;
        int code = q * 256 + cb * 64 + nt * 16 + (lane & 15);
        int d    = (lane >> 4) * 8 + kk * 32 + j;
        P[o] = (_Float16)(E[code * DIM + d] * 1024.0f);   // exact scaling, RN
    }

    __syncthreads();
    for (int s = 128; s > 0; s >>= 1) {
        if (t < s) red[t] += red[t + s];
        __syncthreads();
    }
    if (t == 0) { e2[b] = (float)red[0]; e2p[b] = (float)(red[0] * 1048576.0); }

    int o = b * 256 + t;
    int d = o >> 10, k = o & 1023;
    Et[o] = E[k * DIM + d];

    if (b < 4) counts[b * 256 + t] = 0;
    if (b == 0 && t == 0) { *loss = 0.0; *rcnt = 0; }
}

// ---------------------------------------------------------------------------
// main: MFMA ranking, single f16 product xh*Eh (numerics identical to r8/r9).
// r10: B stream staged via ASYNC global_load_lds into a per-wave LDS double
// buffer, 2 steps ahead, with counted s_waitcnt vmcnt(4) (never 0 mid-loop).
// This hides the ~450cyc L2 load latency within a single wave — r9 showed
// plain-C register prefetch gets re-scheduled away by the compiler.
// e2p staged to LDS so no stray vmem ops pollute the vmcnt count.
// OCCUPANCY NOTE (r4-r7): never use a min-waves launch bound here (spills).
// grid 1024 x 256
__launch_bounds__(256)
__global__ void k_main(const float* __restrict__ X, const _Float16* __restrict__ P,
                       const float* __restrict__ e2p,
                       int* __restrict__ idx_ws, int* __restrict__ rlist,
                       int* __restrict__ rcnt) {
    __shared__ __align__(16) char sAll[70656];
    const int tid  = threadIdx.x;
    const int wid  = tid >> 6;
    const int lane = tid & 63;
    const int c16  = lane & 15;
    const int kg   = lane >> 4;
    const int rb   = blockIdx.x * RPB;

    char* sA = sAll + LDS_X;

    // ---- stage X -> f16 in LDS; stage e2p -> LDS ----
    {
        const float4* Xg = (const float4*)(X + (size_t)rb * DIM);
        #pragma unroll
        for (int it = 0; it < 16; ++it) {
            int f = it * 256 + tid;
            int row = f >> 6, d4 = f & 63;
            float4 v = Xg[(size_t)row * 64 + d4];
            half4 hh = {(_Float16)v.x, (_Float16)v.y, (_Float16)v.z, (_Float16)v.w};
            *(half4*)(sA + row * ROWB + d4 * 8) = hh;
        }
        ((float4*)(sAll + LDS_E2))[tid] = ((const float4*)e2p)[tid];
    }

    // ---- async B prologue: steps 0,1 into the double buffer ----
    const char* gB = (const char*)P + (size_t)wid * 131072 + (size_t)lane * 16;
    char*       lB = sAll + LDS_B + wid * 8192;
#define GLL(ss, nt)                                                                          \
    __builtin_amdgcn_global_load_lds(                                                        \
        (const __attribute__((address_space(1))) unsigned int*)(gB + (size_t)(((ss) * 4 + (nt)) * 1024)), \
        (__attribute__((address_space(3))) unsigned int*)(lB + (((ss) & 1) * 4096 + (nt) * 1024)),        \
        16, 0, 0)
    GLL(0, 0); GLL(0, 1); GLL(0, 2); GLL(0, 3);
    GLL(1, 0); GLL(1, 1); GLL(1, 2); GLL(1, 3);

    __syncthreads();   // drains all counters (incl. prologue) — counting below
                       // assumes only our in-loop GLLs are outstanding.

    int Abase[4];
    #pragma unroll
    for (int mt = 0; mt < 4; ++mt) Abase[mt] = (mt * 16 + c16) * ROWB + kg * 16;

    float tb1[16], tb2[16];
    int   ti1[16];
    #pragma unroll
    for (int i = 0; i < 16; ++i) { tb1[i] = 3.4e38f; tb2[i] = 3.4e38f; ti1[i] = 0; }

    const int cw = wid * 256;
    const float* sE2 = (const float*)(sAll + LDS_E2);

    f32x4 acc[4][4];

    #pragma unroll
    for (int s = 0; s < 32; ++s) {
        const int cb = s >> 3, kk = s & 7;
        if (kk == 0) {
            #pragma unroll
            for (int mt = 0; mt < 4; ++mt)
                #pragma unroll
                for (int nt = 0; nt < 4; ++nt) acc[mt][nt] = 0.0f;
        }
        // wait for this step's B tile (issued 2 steps ago). Counted wait:
        // outstanding entering step s = {S_s, S_{s+1}} = 8 loads; vmcnt(4)
        // drains S_s. Last step: only S_31 outstanding -> vmcnt(0).
        if (s == 31) { asm volatile("s_waitcnt vmcnt(0)" ::: "memory"); }
        else         { asm volatile("s_waitcnt vmcnt(4)" ::: "memory"); }
        __builtin_amdgcn_sched_barrier(0);

        const char* bb = lB + (s & 1) * 4096 + (size_t)lane * 16;
        half8 b0 = *(const half8*)(bb);
        half8 b1 = *(const half8*)(bb + 1024);
        half8 b2 = *(const half8*)(bb + 2048);
        half8 b3 = *(const half8*)(bb + 3072);
        half8 ah[4];
        #pragma unroll
        for (int mt = 0; mt < 4; ++mt)
            ah[mt] = *(const half8*)(sA + Abase[mt] + kk * 64);

        // all LDS reads of buf[s&1] must land in regs before we overwrite it
        asm volatile("s_waitcnt lgkmcnt(0)" ::: "memory");
        __builtin_amdgcn_sched_barrier(0);
        if (s < 30) { GLL(s + 2, 0); GLL(s + 2, 1); GLL(s + 2, 2); GLL(s + 2, 3); }
        __builtin_amdgcn_sched_barrier(0);

        #pragma unroll
        for (int mt = 0; mt < 4; ++mt) {
            acc[mt][0] = __builtin_amdgcn_mfma_f32_16x16x32_f16(ah[mt], b0, acc[mt][0], 0, 0, 0);
            acc[mt][1] = __builtin_amdgcn_mfma_f32_16x16x32_f16(ah[mt], b1, acc[mt][1], 0, 0, 0);
            acc[mt][2] = __builtin_amdgcn_mfma_f32_16x16x32_f16(ah[mt], b2, acc[mt][2], 0, 0, 0);
            acc[mt][3] = __builtin_amdgcn_mfma_f32_16x16x32_f16(ah[mt], b3, acc[mt][3], 0, 0, 0);
        }

        if (kk == 7) {
            // epilogue: s' = e2' - 2048*dot', sorted-insert top-2
            const int cbase = cw + cb * 64;
            const int c0 = cbase + c16;
            float e2v[4];
            #pragma unroll
            for (int nt = 0; nt < 4; ++nt) e2v[nt] = sE2[c0 + nt * 16];
            #pragma unroll
            for (int mt = 0; mt < 4; ++mt)
                #pragma unroll
                for (int nt = 0; nt < 4; ++nt) {
                    int code = cbase + nt * 16 + c16;
                    #pragma unroll
                    for (int r = 0; r < 4; ++r) {
                        float sc = fmaf(-2048.0f, acc[mt][nt][r], e2v[nt]);
                        int ix = mt * 4 + r;
                        float hi = fmaxf(tb1[ix], sc);
                        tb2[ix] = fminf(tb2[ix], hi);
                        bool lt = sc < tb1[ix];
                        tb1[ix] = lt ? sc : tb1[ix];
                        ti1[ix] = lt ? code : ti1[ix];
                    }
                }
        }
    }
#undef GLL

    // ---- butterfly merge across the 16 col-lanes of each kg group ----
    #pragma unroll
    for (int ix = 0; ix < 16; ++ix) {
        float v1 = tb1[ix], v2 = tb2[ix];
        int   j1 = ti1[ix];
        #pragma unroll
        for (int m = 1; m < 16; m <<= 1) {
            float ov1 = __shfl_xor(v1, m, 64);
            int   oj1 = __shfl_xor(j1, m, 64);
            float ov2 = __shfl_xor(v2, m, 64);
            bool take = (ov1 < v1) || (ov1 == v1 && oj1 < j1);
            float losr = take ? v1 : ov1;
            v1 = take ? ov1 : v1;
            j1 = take ? oj1 : j1;
            v2 = fminf(fminf(v2, ov2), losr);
        }
        tb1[ix] = v1; tb2[ix] = v2; ti1[ix] = j1;
    }

    // ---- cross-wave merge via LDS (reuse sA region) ----
    __syncthreads();
    float* mB1 = (float*)sA;            // [64][4]
    float* mB2 = (float*)(sA + 1024);   // [64][4]
    int*   mI1 = (int*)(sA + 2048);     // [64][4]
    #pragma unroll
    for (int ix = 0; ix < 16; ++ix) {
        if (c16 == ix) {
            int row = (ix >> 2) * 16 + kg * 4 + (ix & 3);
            mB1[row * 4 + wid] = tb1[ix];
            mB2[row * 4 + wid] = tb2[ix];
            mI1[row * 4 + wid] = ti1[ix];
        }
    }
    __syncthreads();
    if (tid < RPB) {
        float m1 = 3.4e38f, m2 = 3.4e38f;
        int mi = 0;
        #pragma unroll
        for (int w = 0; w < 4; ++w) {
            float v = mB1[tid * 4 + w];
            int  id = mI1[tid * 4 + w];
            float u = mB2[tid * 4 + w];
            bool take = (v < m1) || (v == m1 && id < mi);
            float losr = take ? m1 : v;
            m1 = take ? v : m1;
            mi = take ? id : mi;
            m2 = fminf(fminf(m2, u), losr);
        }
        int g = rb + tid;
        idx_ws[g] = mi;
        if (m2 - m1 < TAUP) {
            int slot = atomicAdd(rcnt, 1);
            rlist[slot] = g;
        }
    }
}

// ---------------------------------------------------------------------------
// refine: exact reference-fp32 replication, 4 rows per Et sweep (r10).
// r9's 8-row batch spilled its 32 fp64 accs (VGPR 64, ~10GB scratch, 224µs);
// 4 rows = 16 doubles = 32 VGPRs fits. (256,1) relaxes the allocator to the
// full 512-reg budget (anti-spill — the OPPOSITE of the r4/r6 min-waves trap).
// Per-row fp64 accumulation order over d is UNCHANGED.
// grid 512 x 256
__launch_bounds__(256, 1)
__global__ void k_refine(const float* __restrict__ X, const float* __restrict__ Et,
                         const float* __restrict__ e2,
                         const int* __restrict__ rlist, const int* __restrict__ rcnt,
                         int* __restrict__ idx_ws) {
    __shared__ float xs[4][256];
    __shared__ float sbv[4][256];
    __shared__ int   sbi[4][256];
    __shared__ float x2s[4];
    __shared__ int   rows[4];
    const int cnt = *rcnt;
    const int t = threadIdx.x;
    for (int base = blockIdx.x * 4; base < cnt; base += gridDim.x * 4) {
        __syncthreads();
        if (t < 4) {
            int e = base + t;
            rows[t] = rlist[e < cnt ? e : (cnt - 1)];
        }
        __syncthreads();
        // stage 4 rows of X (256 float4 slots)
        ((float4*)xs[t >> 6])[t & 63] =
            ((const float4*)(X + (size_t)rows[t >> 6] * DIM))[t & 63];
        __syncthreads();
        // x2_32 per row (fp64 serial over d, fl32) — same order as reference path
        if (t < 4) {
            double s = 0.0;
            for (int d = 0; d < DIM; ++d) { double xv = (double)xs[t][d]; s += xv * xv; }
            x2s[t] = (float)s;
        }
        __syncthreads();

        // fp64 dots: thread t owns codes {t, t+256, t+512, t+768} for 4 rows
        double a0[4], a1[4], a2[4], a3[4];
        #pragma unroll
        for (int r = 0; r < 4; ++r) { a0[r] = 0.0; a1[r] = 0.0; a2[r] = 0.0; a3[r] = 0.0; }
        for (int d = 0; d < DIM; ++d) {
            double e0 = (double)Et[d * KCODES + t];
            double e1 = (double)Et[d * KCODES + 256 + t];
            double e2d = (double)Et[d * KCODES + 512 + t];
            double e3 = (double)Et[d * KCODES + 768 + t];
            #pragma unroll
            for (int r = 0; r < 4; ++r) {
                double xv = (double)xs[r][d];
                a0[r] += xv * e0;
                a1[r] += xv * e1;
                a2[r] += xv * e2d;
                a3[r] += xv * e3;
            }
        }

        // per-thread best over its 4 codes, per row (fp32-replicated pipeline)
        const float eA = e2[t], eB = e2[256 + t], eC = e2[512 + t], eD = e2[768 + t];
        #pragma unroll
        for (int r = 0; r < 4; ++r) {
            float best = 3.4e38f; int bk = 0;
            float x2 = x2s[r];
            { float d2 = fmaf(-2.f, (float)a0[r], x2 + eA); if (d2 < best) { best = d2; bk = t; } }
            { float d2 = fmaf(-2.f, (float)a1[r], x2 + eB); if (d2 < best) { best = d2; bk = 256 + t; } }
            { float d2 = fmaf(-2.f, (float)a2[r], x2 + eC); if (d2 < best) { best = d2; bk = 512 + t; } }
            { float d2 = fmaf(-2.f, (float)a3[r], x2 + eD); if (d2 < best) { best = d2; bk = 768 + t; } }
            sbv[r][t] = best; sbi[r][t] = bk;
        }
        __syncthreads();
        // final reduce: wave w handles row w
        {
            const int w = t >> 6, lane = t & 63;
            float v = sbv[w][lane];     int id = sbi[w][lane];
            #pragma unroll
            for (int c = 1; c < 4; ++c) {
                float ov = sbv[w][lane + 64 * c]; int oi = sbi[w][lane + 64 * c];
                if (ov < v || (ov == v && oi < id)) { v = ov; id = oi; }
            }
            #pragma unroll
            for (int m = 1; m < 64; m <<= 1) {
                float ov = __shfl_xor(v, m, 64);
                int   oi = __shfl_xor(id, m, 64);
                if (ov < v || (ov == v && oi < id)) { v = ov; id = oi; }
            }
            if (lane == 0 && base + w < cnt) idx_ws[rows[w]] = id;
        }
    }
}

// ---------------------------------------------------------------------------
// out: quantized rows, index output, loss, histogram. One fp64 atomic/block.
// grid 1024 x 256
__launch_bounds__(256)
__global__ void k_out(const float* __restrict__ X, const float* __restrict__ E,
                      const int* __restrict__ idx_ws, float* __restrict__ out,
                      int* __restrict__ counts, double* __restrict__ loss) {
    const int tid = threadIdx.x;
    const int w = tid >> 6, lane = tid & 63;
    const int rbase = blockIdx.x * 64;
    double ls = 0.0;
    #pragma unroll 4
    for (int it = 0; it < 16; ++it) {
        const int row = rbase + it * 4 + w;
        const int k = idx_ws[row];
        float4 q = ((const float4*)(E + (size_t)k * DIM))[lane];
        float4 x = ((const float4*)(X + (size_t)row * DIM))[lane];
        ((float4*)(out + (size_t)row * DIM))[lane] = q;
        double d0 = (double)q.x - (double)x.x;
        double d1 = (double)q.y - (double)x.y;
        double d2 = (double)q.z - (double)x.z;
        double d3 = (double)q.w - (double)x.w;
        ls += d0 * d0 + d1 * d1 + d2 * d2 + d3 * d3;
        if (lane == 0) {
            atomicAdd(&counts[k], 1);
            out[OUT_IDX + row] = (float)k;
        }
    }
    __shared__ double red[256];
    red[tid] = ls;
    __syncthreads();
    for (int s = 128; s > 0; s >>= 1) {
        if (tid < s) red[tid] += red[tid + s];
        __syncthreads();
    }
    if (tid == 0) atomicAdd(loss, red[0]);
}

// ---------------------------------------------------------------------------
// fin: scalars
__global__ void k_fin(const int* __restrict__ counts, const double* __restrict__ loss,
                      float* __restrict__ out) {
    int t = threadIdx.x;
    __shared__ double red[256];
    double h = 0.0;
    #pragma unroll
    for (int i = 0; i < 4; ++i) {
        double p = (double)counts[t + i * 256] / (double)N_ROWS;
        h += p * log(p + 1e-10);
    }
    red[t] = h;
    __syncthreads();
    for (int s = 128; s > 0; s >>= 1) {
        if (t < s) red[t] += red[t + s];
        __syncthreads();
    }
    if (t == 0) {
        out[OUT_PERP] = (float)exp(-red[0]);
        out[OUT_LOSS] = (float)((*loss) / (double)Q_SIZE * 1.25);
    }
}

// ---------------------------------------------------------------------------
extern "C" void kernel_launch(void* const* d_in, const int* in_sizes, int n_in,
                              void* d_out, int out_size, void* d_ws, size_t ws_size,
                              hipStream_t stream) {
    (void)in_sizes; (void)n_in; (void)out_size; (void)ws_size;
    const float* X = (const float*)d_in[0];
    const float* E = (const float*)d_in[1];
    float* out = (float*)d_out;
    char* ws = (char*)d_ws;

    double*    loss   = (double*)(ws + WS_LOSS);
    int*       rcnt   = (int*)(ws + WS_RCNT);
    float*     e2     = (float*)(ws + WS_E2);
    float*     e2p    = (float*)(ws + WS_E2P);
    int*       counts = (int*)(ws + WS_COUNTS);
    int*       idx_ws = (int*)(ws + WS_IDX);
    int*       rlist  = (int*)(ws + WS_RLIST);
    float*     Et     = (float*)(ws + WS_ET);
    _Float16*  Pp     = (_Float16*)(ws + WS_P);

    k_prep<<<1024, 256, 0, stream>>>(E, e2, e2p, Et, Pp, counts, loss, rcnt);
    k_main<<<N_ROWS / RPB, 256, 0, stream>>>(X, Pp, e2p, idx_ws, rlist, rcnt);
    k_refine<<<512, 256, 0, stream>>>(X, Et, e2, rlist, rcnt, idx_ws);
    k_out<<<1024, 256, 0, stream>>>(X, E, idx_ws, out, counts, loss);
    k_fin<<<1, 256, 0, stream>>>(counts, loss, out);
}

// Round 11
// 185.940 us; speedup vs baseline: 2.1670x; 1.0670x over previous
//
#include <hip/hip_runtime.h>
#include <math.h>

#define N_ROWS   65536
#define DIM      256
#define KCODES   1024
#define Q_SIZE   (N_ROWS * DIM)          // 16777216
#define OUT_LOSS Q_SIZE
#define OUT_PERP (Q_SIZE + 1)
#define OUT_IDX  (Q_SIZE + 2)

// flag threshold in scaled-score units (s' = 2^20 * d2-units). Same as r8 (passed).
#define TAUP 200.0f

// ws layout (bytes)
#define WS_LOSS   0        // double
#define WS_RCNT   8        // int
#define WS_E2     16       // float[1024]  original units
#define WS_E2P    4112     // float[1024]  scaled by 2^20
#define WS_COUNTS 8208     // int[1024]
#define WS_IDX    12304    // int[65536]
#define WS_RLIST  274448   // int[65536]
#define WS_ET     536592   // float[262144]   E^T fp32 (refine)
#define WS_P      1585168  // _Float16[262144] packed f16(1024*E) per-wave linear

typedef _Float16 half8 __attribute__((ext_vector_type(8)));
typedef _Float16 half4 __attribute__((ext_vector_type(4)));
typedef float    f32x4 __attribute__((ext_vector_type(4)));

#define ROWB 528    // LDS bytes per X row: 512 (xh) + 16 pad
#define RPB  32     // rows per block (r11: 32 -> LDS 53760B = 3 blocks/CU)

// k_main LDS carve: X 16896 | e2p 4096 | B dbuf 32768 = 53760 B (3/CU: 161280<=163840)
#define LDS_X  0
#define LDS_E2 16896
#define LDS_B  20992

// ---------------------------------------------------------------------------
// prep: e2, e2p, Et (fp32 transpose, refine), packed P; zero accums.
// P layout: P[q][cb][kk][nt][lane][8 halfs] — per-wave linear B-frag stream;
// each 1KB chunk is exactly lane-linear (lane*16B) => global_load_lds-ready.
// grid 1024 x 256
__global__ void k_prep(const float* __restrict__ E, float* __restrict__ e2,
                       float* __restrict__ e2p, float* __restrict__ Et,
                       _Float16* __restrict__ P,
                       int* __restrict__ counts, double* __restrict__ loss,
                       int* __restrict__ rcnt) {
    int b = blockIdx.x, t = threadIdx.x;
    __shared__ double red[256];
    float v = E[b * DIM + t];
    red[t] = (double)v * (double)v;

    {   // packed B-stream write
        int o   = b * 256 + t;
        int j    = o & 7;
        int lane = (o >> 3) & 63;
        int nt   = (o >> 9) & 3;
        int kk   = (o >> 11) & 7;
        int cbq  = o >> 14;            // 0..15
        int q = cbq >> 2, cb = cbq & 3;
        int code = q * 256 + cb * 64 + nt * 16 + (lane & 15);
        int d    = (lane >> 4) * 8 + kk * 32 + j;
        P[o] = (_Float16)(E[code * DIM + d] * 1024.0f);   // exact scaling, RN
    }

    __syncthreads();
    for (int s = 128; s > 0; s >>= 1) {
        if (t < s) red[t] += red[t + s];
        __syncthreads();
    }
    if (t == 0) { e2[b] = (float)red[0]; e2p[b] = (float)(red[0] * 1048576.0); }

    int o = b * 256 + t;
    int d = o >> 10, k = o & 1023;
    Et[o] = E[k * DIM + d];

    if (b < 4) counts[b * 256 + t] = 0;
    if (b == 0 && t == 0) { *loss = 0.0; *rcnt = 0; }
}

// ---------------------------------------------------------------------------
// main: MFMA ranking, single f16 product xh*Eh (numerics identical to r8-r10).
// r11: RPB 64->32 (LDS 53760B -> 3 blocks/CU, +50% residency; r10 was
// latency-bound with no pipe >50%). Async global_load_lds B double-buffer,
// counted vmcnt(4) (never 0 mid-loop), unchanged from r10.
// OCCUPANCY NOTE (r4-r7): never use a min-waves launch bound here (spills).
// grid 2048 x 256
__launch_bounds__(256)
__global__ void k_main(const float* __restrict__ X, const _Float16* __restrict__ P,
                       const float* __restrict__ e2p,
                       int* __restrict__ idx_ws, int* __restrict__ rlist,
                       int* __restrict__ rcnt) {
    __shared__ __align__(16) char sAll[53760];
    const int tid  = threadIdx.x;
    const int wid  = tid >> 6;
    const int lane = tid & 63;
    const int c16  = lane & 15;
    const int kg   = lane >> 4;
    const int rb   = blockIdx.x * RPB;

    char* sA = sAll + LDS_X;

    // ---- stage X -> f16 in LDS; stage e2p -> LDS ----
    {
        const float4* Xg = (const float4*)(X + (size_t)rb * DIM);
        #pragma unroll
        for (int it = 0; it < 8; ++it) {
            int f = it * 256 + tid;
            int row = f >> 6, d4 = f & 63;
            float4 v = Xg[(size_t)row * 64 + d4];
            half4 hh = {(_Float16)v.x, (_Float16)v.y, (_Float16)v.z, (_Float16)v.w};
            *(half4*)(sA + row * ROWB + d4 * 8) = hh;
        }
        ((float4*)(sAll + LDS_E2))[tid] = ((const float4*)e2p)[tid];
    }

    // ---- async B prologue: steps 0,1 into the double buffer ----
    const char* gB = (const char*)P + (size_t)wid * 131072 + (size_t)lane * 16;
    char*       lB = sAll + LDS_B + wid * 8192;
#define GLL(ss, nt)                                                                          \
    __builtin_amdgcn_global_load_lds(                                                        \
        (const __attribute__((address_space(1))) unsigned int*)(gB + (size_t)(((ss) * 4 + (nt)) * 1024)), \
        (__attribute__((address_space(3))) unsigned int*)(lB + (((ss) & 1) * 4096 + (nt) * 1024)),        \
        16, 0, 0)
    GLL(0, 0); GLL(0, 1); GLL(0, 2); GLL(0, 3);
    GLL(1, 0); GLL(1, 1); GLL(1, 2); GLL(1, 3);

    __syncthreads();   // drains all counters (incl. prologue) — counting below
                       // assumes only our in-loop GLLs are outstanding.

    int Abase[2];
    #pragma unroll
    for (int mt = 0; mt < 2; ++mt) Abase[mt] = (mt * 16 + c16) * ROWB + kg * 16;

    float tb1[8], tb2[8];
    int   ti1[8];
    #pragma unroll
    for (int i = 0; i < 8; ++i) { tb1[i] = 3.4e38f; tb2[i] = 3.4e38f; ti1[i] = 0; }

    const int cw = wid * 256;
    const float* sE2 = (const float*)(sAll + LDS_E2);

    f32x4 acc[2][4];

    #pragma unroll
    for (int s = 0; s < 32; ++s) {
        const int cb = s >> 3, kk = s & 7;
        if (kk == 0) {
            #pragma unroll
            for (int mt = 0; mt < 2; ++mt)
                #pragma unroll
                for (int nt = 0; nt < 4; ++nt) acc[mt][nt] = 0.0f;
        }
        // wait for this step's B tile (issued 2 steps ago). Counted wait:
        // outstanding entering step s = {S_s, S_{s+1}} = 8 loads; vmcnt(4)
        // drains S_s. Last step: only S_31 outstanding -> vmcnt(0).
        if (s == 31) { asm volatile("s_waitcnt vmcnt(0)" ::: "memory"); }
        else         { asm volatile("s_waitcnt vmcnt(4)" ::: "memory"); }
        __builtin_amdgcn_sched_barrier(0);

        const char* bb = lB + (s & 1) * 4096 + (size_t)lane * 16;
        half8 b0 = *(const half8*)(bb);
        half8 b1 = *(const half8*)(bb + 1024);
        half8 b2 = *(const half8*)(bb + 2048);
        half8 b3 = *(const half8*)(bb + 3072);
        half8 ah[2];
        #pragma unroll
        for (int mt = 0; mt < 2; ++mt)
            ah[mt] = *(const half8*)(sA + Abase[mt] + kk * 64);

        // all LDS reads of buf[s&1] must land in regs before we overwrite it
        asm volatile("s_waitcnt lgkmcnt(0)" ::: "memory");
        __builtin_amdgcn_sched_barrier(0);
        if (s < 30) { GLL(s + 2, 0); GLL(s + 2, 1); GLL(s + 2, 2); GLL(s + 2, 3); }
        __builtin_amdgcn_sched_barrier(0);

        #pragma unroll
        for (int mt = 0; mt < 2; ++mt) {
            acc[mt][0] = __builtin_amdgcn_mfma_f32_16x16x32_f16(ah[mt], b0, acc[mt][0], 0, 0, 0);
            acc[mt][1] = __builtin_amdgcn_mfma_f32_16x16x32_f16(ah[mt], b1, acc[mt][1], 0, 0, 0);
            acc[mt][2] = __builtin_amdgcn_mfma_f32_16x16x32_f16(ah[mt], b2, acc[mt][2], 0, 0, 0);
            acc[mt][3] = __builtin_amdgcn_mfma_f32_16x16x32_f16(ah[mt], b3, acc[mt][3], 0, 0, 0);
        }

        if (kk == 7) {
            // epilogue: s' = e2' - 2048*dot', sorted-insert top-2
            const int cbase = cw + cb * 64;
            const int c0 = cbase + c16;
            float e2v[4];
            #pragma unroll
            for (int nt = 0; nt < 4; ++nt) e2v[nt] = sE2[c0 + nt * 16];
            #pragma unroll
            for (int mt = 0; mt < 2; ++mt)
                #pragma unroll
                for (int nt = 0; nt < 4; ++nt) {
                    int code = cbase + nt * 16 + c16;
                    #pragma unroll
                    for (int r = 0; r < 4; ++r) {
                        float sc = fmaf(-2048.0f, acc[mt][nt][r], e2v[nt]);
                        int ix = mt * 4 + r;
                        float hi = fmaxf(tb1[ix], sc);
                        tb2[ix] = fminf(tb2[ix], hi);
                        bool lt = sc < tb1[ix];
                        tb1[ix] = lt ? sc : tb1[ix];
                        ti1[ix] = lt ? code : ti1[ix];
                    }
                }
        }
    }
#undef GLL

    // ---- butterfly merge across the 16 col-lanes of each kg group ----
    #pragma unroll
    for (int ix = 0; ix < 8; ++ix) {
        float v1 = tb1[ix], v2 = tb2[ix];
        int   j1 = ti1[ix];
        #pragma unroll
        for (int m = 1; m < 16; m <<= 1) {
            float ov1 = __shfl_xor(v1, m, 64);
            int   oj1 = __shfl_xor(j1, m, 64);
            float ov2 = __shfl_xor(v2, m, 64);
            bool take = (ov1 < v1) || (ov1 == v1 && oj1 < j1);
            float losr = take ? v1 : ov1;
            v1 = take ? ov1 : v1;
            j1 = take ? oj1 : j1;
            v2 = fminf(fminf(v2, ov2), losr);
        }
        tb1[ix] = v1; tb2[ix] = v2; ti1[ix] = j1;
    }

    // ---- cross-wave merge via LDS (reuse sA region) ----
    __syncthreads();
    float* mB1 = (float*)sA;            // [32][4]
    float* mB2 = (float*)(sA + 512);    // [32][4]
    int*   mI1 = (int*)(sA + 1024);     // [32][4]
    #pragma unroll
    for (int ix = 0; ix < 8; ++ix) {
        if (c16 == ix) {
            int row = (ix >> 2) * 16 + kg * 4 + (ix & 3);
            mB1[row * 4 + wid] = tb1[ix];
            mB2[row * 4 + wid] = tb2[ix];
            mI1[row * 4 + wid] = ti1[ix];
        }
    }
    __syncthreads();
    if (tid < RPB) {
        float m1 = 3.4e38f, m2 = 3.4e38f;
        int mi = 0;
        #pragma unroll
        for (int w = 0; w < 4; ++w) {
            float v = mB1[tid * 4 + w];
            int  id = mI1[tid * 4 + w];
            float u = mB2[tid * 4 + w];
            bool take = (v < m1) || (v == m1 && id < mi);
            float losr = take ? m1 : v;
            m1 = take ? v : m1;
            mi = take ? id : mi;
            m2 = fminf(fminf(m2, u), losr);
        }
        int g = rb + tid;
        idx_ws[g] = mi;
        if (m2 - m1 < TAUP) {
            int slot = atomicAdd(rcnt, 1);
            rlist[slot] = g;
        }
    }
}

// ---------------------------------------------------------------------------
// refine: exact reference-fp32 replication, 4 rows per Et sweep.
// r11: d-loop unrolled x4 (r10 was a ~250cyc/iter serial L2 latency chain —
// 4 loads, wait, 16 FMAs; unroll batches 16 independent loads) and grid 1024
// so every block runs <=1 batch at cnt<=4096. fp64 accumulation order per
// accumulator is UNCHANGED (unroll does not reassociate).
// grid 1024 x 256
__launch_bounds__(256, 1)
__global__ void k_refine(const float* __restrict__ X, const float* __restrict__ Et,
                         const float* __restrict__ e2,
                         const int* __restrict__ rlist, const int* __restrict__ rcnt,
                         int* __restrict__ idx_ws) {
    __shared__ float xs[4][256];
    __shared__ float sbv[4][256];
    __shared__ int   sbi[4][256];
    __shared__ float x2s[4];
    __shared__ int   rows[4];
    const int cnt = *rcnt;
    const int t = threadIdx.x;
    for (int base = blockIdx.x * 4; base < cnt; base += gridDim.x * 4) {
        __syncthreads();
        if (t < 4) {
            int e = base + t;
            rows[t] = rlist[e < cnt ? e : (cnt - 1)];
        }
        __syncthreads();
        // stage 4 rows of X (256 float4 slots)
        ((float4*)xs[t >> 6])[t & 63] =
            ((const float4*)(X + (size_t)rows[t >> 6] * DIM))[t & 63];
        __syncthreads();
        // x2_32 per row (fp64 serial over d, fl32) — same order as reference path
        if (t < 4) {
            double s = 0.0;
            for (int d = 0; d < DIM; ++d) { double xv = (double)xs[t][d]; s += xv * xv; }
            x2s[t] = (float)s;
        }
        __syncthreads();

        // fp64 dots: thread t owns codes {t, t+256, t+512, t+768} for 4 rows
        double a0[4], a1[4], a2[4], a3[4];
        #pragma unroll
        for (int r = 0; r < 4; ++r) { a0[r] = 0.0; a1[r] = 0.0; a2[r] = 0.0; a3[r] = 0.0; }
        #pragma unroll 4
        for (int d = 0; d < DIM; ++d) {
            double e0 = (double)Et[d * KCODES + t];
            double e1 = (double)Et[d * KCODES + 256 + t];
            double e2d = (double)Et[d * KCODES + 512 + t];
            double e3 = (double)Et[d * KCODES + 768 + t];
            #pragma unroll
            for (int r = 0; r < 4; ++r) {
                double xv = (double)xs[r][d];
                a0[r] += xv * e0;
                a1[r] += xv * e1;
                a2[r] += xv * e2d;
                a3[r] += xv * e3;
            }
        }

        // per-thread best over its 4 codes, per row (fp32-replicated pipeline)
        const float eA = e2[t], eB = e2[256 + t], eC = e2[512 + t], eD = e2[768 + t];
        #pragma unroll
        for (int r = 0; r < 4; ++r) {
            float best = 3.4e38f; int bk = 0;
            float x2 = x2s[r];
            { float d2 = fmaf(-2.f, (float)a0[r], x2 + eA); if (d2 < best) { best = d2; bk = t; } }
            { float d2 = fmaf(-2.f, (float)a1[r], x2 + eB); if (d2 < best) { best = d2; bk = 256 + t; } }
            { float d2 = fmaf(-2.f, (float)a2[r], x2 + eC); if (d2 < best) { best = d2; bk = 512 + t; } }
            { float d2 = fmaf(-2.f, (float)a3[r], x2 + eD); if (d2 < best) { best = d2; bk = 768 + t; } }
            sbv[r][t] = best; sbi[r][t] = bk;
        }
        __syncthreads();
        // final reduce: wave w handles row w
        {
            const int w = t >> 6, lane = t & 63;
            float v = sbv[w][lane];     int id = sbi[w][lane];
            #pragma unroll
            for (int c = 1; c < 4; ++c) {
                float ov = sbv[w][lane + 64 * c]; int oi = sbi[w][lane + 64 * c];
                if (ov < v || (ov == v && oi < id)) { v = ov; id = oi; }
            }
            #pragma unroll
            for (int m = 1; m < 64; m <<= 1) {
                float ov = __shfl_xor(v, m, 64);
                int   oi = __shfl_xor(id, m, 64);
                if (ov < v || (ov == v && oi < id)) { v = ov; id = oi; }
            }
            if (lane == 0 && base + w < cnt) idx_ws[rows[w]] = id;
        }
    }
}

// ---------------------------------------------------------------------------
// out: quantized rows, index output, loss, histogram. One fp64 atomic/block.
// grid 1024 x 256
__launch_bounds__(256)
__global__ void k_out(const float* __restrict__ X, const float* __restrict__ E,
                      const int* __restrict__ idx_ws, float* __restrict__ out,
                      int* __restrict__ counts, double* __restrict__ loss) {
    const int tid = threadIdx.x;
    const int w = tid >> 6, lane = tid & 63;
    const int rbase = blockIdx.x * 64;
    double ls = 0.0;
    #pragma unroll 4
    for (int it = 0; it < 16; ++it) {
        const int row = rbase + it * 4 + w;
        const int k = idx_ws[row];
        float4 q = ((const float4*)(E + (size_t)k * DIM))[lane];
        float4 x = ((const float4*)(X + (size_t)row * DIM))[lane];
        ((float4*)(out + (size_t)row * DIM))[lane] = q;
        double d0 = (double)q.x - (double)x.x;
        double d1 = (double)q.y - (double)x.y;
        double d2 = (double)q.z - (double)x.z;
        double d3 = (double)q.w - (double)x.w;
        ls += d0 * d0 + d1 * d1 + d2 * d2 + d3 * d3;
        if (lane == 0) {
            atomicAdd(&counts[k], 1);
            out[OUT_IDX + row] = (float)k;
        }
    }
    __shared__ double red[256];
    red[tid] = ls;
    __syncthreads();
    for (int s = 128; s > 0; s >>= 1) {
        if (tid < s) red[tid] += red[tid + s];
        __syncthreads();
    }
    if (tid == 0) atomicAdd(loss, red[0]);
}

// ---------------------------------------------------------------------------
// fin: scalars
__global__ void k_fin(const int* __restrict__ counts, const double* __restrict__ loss,
                      float* __restrict__ out) {
    int t = threadIdx.x;
    __shared__ double red[256];
    double h = 0.0;
    #pragma unroll
    for (int i = 0; i < 4; ++i) {
        double p = (double)counts[t + i * 256] / (double)N_ROWS;
        h += p * log(p + 1e-10);
    }
    red[t] = h;
    __syncthreads();
    for (int s = 128; s > 0; s >>= 1) {
        if (t < s) red[t] += red[t + s];
        __syncthreads();
    }
    if (t == 0) {
        out[OUT_PERP] = (float)exp(-red[0]);
        out[OUT_LOSS] = (float)((*loss) / (double)Q_SIZE * 1.25);
    }
}

// ---------------------------------------------------------------------------
extern "C" void kernel_launch(void* const* d_in, const int* in_sizes, int n_in,
                              void* d_out, int out_size, void* d_ws, size_t ws_size,
                              hipStream_t stream) {
    (void)in_sizes; (void)n_in; (void)out_size; (void)ws_size;
    const float* X = (const float*)d_in[0];
    const float* E = (const float*)d_in[1];
    float* out = (float*)d_out;
    char* ws = (char*)d_ws;

    double*    loss   = (double*)(ws + WS_LOSS);
    int*       rcnt   = (int*)(ws + WS_RCNT);
    float*     e2     = (float*)(ws + WS_E2);
    float*     e2p    = (float*)(ws + WS_E2P);
    int*       counts = (int*)(ws + WS_COUNTS);
    int*       idx_ws = (int*)(ws + WS_IDX);
    int*       rlist  = (int*)(ws + WS_RLIST);
    float*     Et     = (float*)(ws + WS_ET);
    _Float16*  Pp     = (_Float16*)(ws + WS_P);

    k_prep<<<1024, 256, 0, stream>>>(E, e2, e2p, Et, Pp, counts, loss, rcnt);
    k_main<<<N_ROWS / RPB, 256, 0, stream>>>(X, Pp, e2p, idx_ws, rlist, rcnt);
    k_refine<<<1024, 256, 0, stream>>>(X, Et, e2, rlist, rcnt, idx_ws);
    k_out<<<1024, 256, 0, stream>>>(X, E, idx_ws, out, counts, loss);
    k_fin<<<1, 256, 0, stream>>>(counts, loss, out);
}

// Round 12
// 169.076 us; speedup vs baseline: 2.3831x; 1.0997x over previous
//
#include <hip/hip_runtime.h>
#include <math.h>

#define N_ROWS   65536
#define DIM      256
#define KCODES   1024
#define Q_SIZE   (N_ROWS * DIM)          // 16777216
#define OUT_LOSS Q_SIZE
#define OUT_PERP (Q_SIZE + 1)
#define OUT_IDX  (Q_SIZE + 2)

// flag threshold in scaled-score units (s' = 2^20 * d2-units). Same as r8 (passed).
#define TAUP 200.0f

// ws layout (bytes)
#define WS_LOSS   0        // double
#define WS_RCNT   8        // int
#define WS_E2     16       // float[1024]  original units
#define WS_E2P    4112     // float[1024]  scaled by 2^20
#define WS_COUNTS 8208     // int[1024]
#define WS_IDX    12304    // int[65536]
#define WS_RLIST  274448   // int[65536]
#define WS_ET     536592   // float[262144]   E^T fp32 (refine)
#define WS_P      1585168  // _Float16[262144] packed f16(1024*E) per-wave linear

typedef _Float16 half8 __attribute__((ext_vector_type(8)));
typedef _Float16 half4 __attribute__((ext_vector_type(4)));
typedef float    f32x4 __attribute__((ext_vector_type(4)));

#define ROWB 528    // LDS bytes per X row: 512 (xh) + 16 pad
#define RPB  64     // rows per block (r12: back to r10 geometry — fewer blocks,
                    // less per-block fixed overhead; r11's RPB=32 regressed)

// k_main LDS carve: X 33792 | e2p 4096 = 37888 B (no B buffers — B in registers)
#define LDS_X  0
#define LDS_E2 33792

// ---------------------------------------------------------------------------
// prep: e2, e2p, Et (fp32 transpose, refine), packed P; zero accums.
// P layout: P[q][cb][kk][nt][lane][8 halfs] — per-wave linear B-frag stream.
// grid 1024 x 256
__global__ void k_prep(const float* __restrict__ E, float* __restrict__ e2,
                       float* __restrict__ e2p, float* __restrict__ Et,
                       _Float16* __restrict__ P,
                       int* __restrict__ counts, double* __restrict__ loss,
                       int* __restrict__ rcnt) {
    int b = blockIdx.x, t = threadIdx.x;
    __shared__ double red[256];
    float v = E[b * DIM + t];
    red[t] = (double)v * (double)v;

    {   // packed B-stream write
        int o   = b * 256 + t;
        int j    = o & 7;
        int lane = (o >> 3) & 63;
        int nt   = (o >> 9) & 3;
        int kk   = (o >> 11) & 7;
        int cbq  = o >> 14;            // 0..15
        int q = cbq >> 2, cb = cbq & 3;
        int code = q * 256 + cb * 64 + nt * 16 + (lane & 15);
        int d    = (lane >> 4) * 8 + kk * 32 + j;
        P[o] = (_Float16)(E[code * DIM + d] * 1024.0f);   // exact scaling, RN
    }

    __syncthreads();
    for (int s = 128; s > 0; s >>= 1) {
        if (t < s) red[t] += red[t + s];
        __syncthreads();
    }
    if (t == 0) { e2[b] = (float)red[0]; e2p[b] = (float)(red[0] * 1048576.0); }

    int o = b * 256 + t;
    int d = o >> 10, k = o & 1023;
    Et[o] = E[k * DIM + d];

    if (b < 4) counts[b * 256 + t] = 0;
    if (b == 0 && t == 0) { *loss = 0.0; *rcnt = 0; }
}

// ---------------------------------------------------------------------------
// main: MFMA ranking, single f16 product xh*Eh (numerics identical to r8-r11).
// r12: B staged into REGISTERS via inline-asm global_load_dwordx4 (volatile asm
// can't be compiler-sunk — fixes r9), 2-deep rotation, counted vmcnt(4) +
// sched_barrier(0) (rule #18). Kills the per-step lgkmcnt(0) drain and the
// LDS-DMA round trip that r10/r11's global_load_lds path required, and frees
// 32KB LDS (37888 B total -> 4 blocks/CU by LDS).
// OCCUPANCY NOTE (r4-r7): never use a min-waves launch bound here (spills).
// grid 1024 x 256
__launch_bounds__(256)
__global__ void k_main(const float* __restrict__ X, const _Float16* __restrict__ P,
                       const float* __restrict__ e2p,
                       int* __restrict__ idx_ws, int* __restrict__ rlist,
                       int* __restrict__ rcnt) {
    __shared__ __align__(16) char sAll[37888];
    const int tid  = threadIdx.x;
    const int wid  = tid >> 6;
    const int lane = tid & 63;
    const int c16  = lane & 15;
    const int kg   = lane >> 4;
    const int rb   = blockIdx.x * RPB;

    char* sA = sAll + LDS_X;

    // ---- stage X -> f16 in LDS; stage e2p -> LDS ----
    {
        const float4* Xg = (const float4*)(X + (size_t)rb * DIM);
        #pragma unroll
        for (int it = 0; it < 16; ++it) {
            int f = it * 256 + tid;
            int row = f >> 6, d4 = f & 63;
            float4 v = Xg[(size_t)row * 64 + d4];
            half4 hh = {(_Float16)v.x, (_Float16)v.y, (_Float16)v.z, (_Float16)v.w};
            *(half4*)(sA + row * ROWB + d4 * 8) = hh;
        }
        ((float4*)(sAll + LDS_E2))[tid] = ((const float4*)e2p)[tid];
    }
    __syncthreads();   // drains staging vmem — in-loop vmcnt counts only B loads

    // per-wave contiguous B stream: 128 KB per quarter, lane offset 16B
    const char* gB = (const char*)P + (size_t)wid * 131072 + (size_t)lane * 16;
#define GLOAD(dst, ss, nt)                                                    \
    asm volatile("global_load_dwordx4 %0, %1, off"                            \
                 : "=v"(dst)                                                  \
                 : "v"(gB + (size_t)(((ss) * 4 + (nt)) * 1024))               \
                 : "memory")

    half8 bA[4], bB[4], bC[4];
    GLOAD(bA[0], 0, 0); GLOAD(bA[1], 0, 1); GLOAD(bA[2], 0, 2); GLOAD(bA[3], 0, 3);
    GLOAD(bB[0], 1, 0); GLOAD(bB[1], 1, 1); GLOAD(bB[2], 1, 2); GLOAD(bB[3], 1, 3);

    int Abase[4];
    #pragma unroll
    for (int mt = 0; mt < 4; ++mt) Abase[mt] = (mt * 16 + c16) * ROWB + kg * 16;

    float tb1[16], tb2[16];
    int   ti1[16];
    #pragma unroll
    for (int i = 0; i < 16; ++i) { tb1[i] = 3.4e38f; tb2[i] = 3.4e38f; ti1[i] = 0; }

    const int cw = wid * 256;
    const float* sE2 = (const float*)(sAll + LDS_E2);

    f32x4 acc[4][4];

    #pragma unroll
    for (int s = 0; s < 32; ++s) {
        const int cb = s >> 3, kk = s & 7;
        if (kk == 0) {
            #pragma unroll
            for (int mt = 0; mt < 4; ++mt)
                #pragma unroll
                for (int nt = 0; nt < 4; ++nt) acc[mt][nt] = 0.0f;
        }
        // wait for set s (issued 2 steps back). Outstanding entering step s:
        // sets s, s+1 = 8 loads -> vmcnt(4) drains set s. Last step: vmcnt(0).
        if (s == 31) { asm volatile("s_waitcnt vmcnt(0)" ::: "memory"); }
        else         { asm volatile("s_waitcnt vmcnt(4)" ::: "memory"); }
        __builtin_amdgcn_sched_barrier(0);

        // issue set s+2 early (T14) — lands ~2 steps from now
        if (s < 30) {
            GLOAD(bC[0], s + 2, 0); GLOAD(bC[1], s + 2, 1);
            GLOAD(bC[2], s + 2, 2); GLOAD(bC[3], s + 2, 3);
        }

        half8 ah[4];
        #pragma unroll
        for (int mt = 0; mt < 4; ++mt)
            ah[mt] = *(const half8*)(sA + Abase[mt] + kk * 64);

        #pragma unroll
        for (int mt = 0; mt < 4; ++mt) {
            acc[mt][0] = __builtin_amdgcn_mfma_f32_16x16x32_f16(ah[mt], bA[0], acc[mt][0], 0, 0, 0);
            acc[mt][1] = __builtin_amdgcn_mfma_f32_16x16x32_f16(ah[mt], bA[1], acc[mt][1], 0, 0, 0);
            acc[mt][2] = __builtin_amdgcn_mfma_f32_16x16x32_f16(ah[mt], bA[2], acc[mt][2], 0, 0, 0);
            acc[mt][3] = __builtin_amdgcn_mfma_f32_16x16x32_f16(ah[mt], bA[3], acc[mt][3], 0, 0, 0);
        }

        if (kk == 7) {
            // epilogue: s' = e2' - 2048*dot', sorted-insert top-2 (med3 form)
            const int cbase = cw + cb * 64;
            const int c0 = cbase + c16;
            float e2v[4];
            #pragma unroll
            for (int nt = 0; nt < 4; ++nt) e2v[nt] = sE2[c0 + nt * 16];
            #pragma unroll
            for (int mt = 0; mt < 4; ++mt)
                #pragma unroll
                for (int nt = 0; nt < 4; ++nt) {
                    int code = cbase + nt * 16 + c16;
                    #pragma unroll
                    for (int r = 0; r < 4; ++r) {
                        float sc = fmaf(-2048.0f, acc[mt][nt][r], e2v[nt]);
                        int ix = mt * 4 + r;
                        // tb2 = median(tb1, tb2, sc)  == old {hi=max;min} pair
                        tb2[ix] = __builtin_amdgcn_fmed3f(tb1[ix], tb2[ix], sc);
                        bool lt = sc < tb1[ix];
                        tb1[ix] = lt ? sc : tb1[ix];
                        ti1[ix] = lt ? code : ti1[ix];
                    }
                }
        }

        #pragma unroll
        for (int nt = 0; nt < 4; ++nt) { bA[nt] = bB[nt]; bB[nt] = bC[nt]; }
    }
#undef GLOAD

    // ---- butterfly merge across the 16 col-lanes of each kg group ----
    #pragma unroll
    for (int ix = 0; ix < 16; ++ix) {
        float v1 = tb1[ix], v2 = tb2[ix];
        int   j1 = ti1[ix];
        #pragma unroll
        for (int m = 1; m < 16; m <<= 1) {
            float ov1 = __shfl_xor(v1, m, 64);
            int   oj1 = __shfl_xor(j1, m, 64);
            float ov2 = __shfl_xor(v2, m, 64);
            bool take = (ov1 < v1) || (ov1 == v1 && oj1 < j1);
            float losr = take ? v1 : ov1;
            v1 = take ? ov1 : v1;
            j1 = take ? oj1 : j1;
            v2 = fminf(fminf(v2, ov2), losr);
        }
        tb1[ix] = v1; tb2[ix] = v2; ti1[ix] = j1;
    }

    // ---- cross-wave merge via LDS (reuse sA region) ----
    __syncthreads();
    float* mB1 = (float*)sA;            // [64][4]
    float* mB2 = (float*)(sA + 1024);   // [64][4]
    int*   mI1 = (int*)(sA + 2048);     // [64][4]
    #pragma unroll
    for (int ix = 0; ix < 16; ++ix) {
        if (c16 == ix) {
            int row = (ix >> 2) * 16 + kg * 4 + (ix & 3);
            mB1[row * 4 + wid] = tb1[ix];
            mB2[row * 4 + wid] = tb2[ix];
            mI1[row * 4 + wid] = ti1[ix];
        }
    }
    __syncthreads();
    if (tid < RPB) {
        float m1 = 3.4e38f, m2 = 3.4e38f;
        int mi = 0;
        #pragma unroll
        for (int w = 0; w < 4; ++w) {
            float v = mB1[tid * 4 + w];
            int  id = mI1[tid * 4 + w];
            float u = mB2[tid * 4 + w];
            bool take = (v < m1) || (v == m1 && id < mi);
            float losr = take ? m1 : v;
            m1 = take ? v : m1;
            mi = take ? id : mi;
            m2 = fminf(fminf(m2, u), losr);
        }
        int g = rb + tid;
        idx_ws[g] = mi;
        if (m2 - m1 < TAUP) {
            int slot = atomicAdd(rcnt, 1);
            rlist[slot] = g;
        }
    }
}

// ---------------------------------------------------------------------------
// refine: exact reference-fp32 replication, 4 rows per Et sweep, d-loop
// unrolled x4 (r11: fixed the serial L2 chain), grid 1024. fp64 accumulation
// order per accumulator UNCHANGED.
// grid 1024 x 256
__launch_bounds__(256, 1)
__global__ void k_refine(const float* __restrict__ X, const float* __restrict__ Et,
                         const float* __restrict__ e2,
                         const int* __restrict__ rlist, const int* __restrict__ rcnt,
                         int* __restrict__ idx_ws) {
    __shared__ float xs[4][256];
    __shared__ float sbv[4][256];
    __shared__ int   sbi[4][256];
    __shared__ float x2s[4];
    __shared__ int   rows[4];
    const int cnt = *rcnt;
    const int t = threadIdx.x;
    for (int base = blockIdx.x * 4; base < cnt; base += gridDim.x * 4) {
        __syncthreads();
        if (t < 4) {
            int e = base + t;
            rows[t] = rlist[e < cnt ? e : (cnt - 1)];
        }
        __syncthreads();
        ((float4*)xs[t >> 6])[t & 63] =
            ((const float4*)(X + (size_t)rows[t >> 6] * DIM))[t & 63];
        __syncthreads();
        if (t < 4) {
            double s = 0.0;
            for (int d = 0; d < DIM; ++d) { double xv = (double)xs[t][d]; s += xv * xv; }
            x2s[t] = (float)s;
        }
        __syncthreads();

        double a0[4], a1[4], a2[4], a3[4];
        #pragma unroll
        for (int r = 0; r < 4; ++r) { a0[r] = 0.0; a1[r] = 0.0; a2[r] = 0.0; a3[r] = 0.0; }
        #pragma unroll 4
        for (int d = 0; d < DIM; ++d) {
            double e0 = (double)Et[d * KCODES + t];
            double e1 = (double)Et[d * KCODES + 256 + t];
            double e2d = (double)Et[d * KCODES + 512 + t];
            double e3 = (double)Et[d * KCODES + 768 + t];
            #pragma unroll
            for (int r = 0; r < 4; ++r) {
                double xv = (double)xs[r][d];
                a0[r] += xv * e0;
                a1[r] += xv * e1;
                a2[r] += xv * e2d;
                a3[r] += xv * e3;
            }
        }

        const float eA = e2[t], eB = e2[256 + t], eC = e2[512 + t], eD = e2[768 + t];
        #pragma unroll
        for (int r = 0; r < 4; ++r) {
            float best = 3.4e38f; int bk = 0;
            float x2 = x2s[r];
            { float d2 = fmaf(-2.f, (float)a0[r], x2 + eA); if (d2 < best) { best = d2; bk = t; } }
            { float d2 = fmaf(-2.f, (float)a1[r], x2 + eB); if (d2 < best) { best = d2; bk = 256 + t; } }
            { float d2 = fmaf(-2.f, (float)a2[r], x2 + eC); if (d2 < best) { best = d2; bk = 512 + t; } }
            { float d2 = fmaf(-2.f, (float)a3[r], x2 + eD); if (d2 < best) { best = d2; bk = 768 + t; } }
            sbv[r][t] = best; sbi[r][t] = bk;
        }
        __syncthreads();
        {
            const int w = t >> 6, lane = t & 63;
            float v = sbv[w][lane];     int id = sbi[w][lane];
            #pragma unroll
            for (int c = 1; c < 4; ++c) {
                float ov = sbv[w][lane + 64 * c]; int oi = sbi[w][lane + 64 * c];
                if (ov < v || (ov == v && oi < id)) { v = ov; id = oi; }
            }
            #pragma unroll
            for (int m = 1; m < 64; m <<= 1) {
                float ov = __shfl_xor(v, m, 64);
                int   oi = __shfl_xor(id, m, 64);
                if (ov < v || (ov == v && oi < id)) { v = ov; id = oi; }
            }
            if (lane == 0 && base + w < cnt) idx_ws[rows[w]] = id;
        }
    }
}

// ---------------------------------------------------------------------------
// out: quantized rows, index output, loss, histogram. One fp64 atomic/block.
// grid 1024 x 256
__launch_bounds__(256)
__global__ void k_out(const float* __restrict__ X, const float* __restrict__ E,
                      const int* __restrict__ idx_ws, float* __restrict__ out,
                      int* __restrict__ counts, double* __restrict__ loss) {
    const int tid = threadIdx.x;
    const int w = tid >> 6, lane = tid & 63;
    const int rbase = blockIdx.x * 64;
    double ls = 0.0;
    #pragma unroll 4
    for (int it = 0; it < 16; ++it) {
        const int row = rbase + it * 4 + w;
        const int k = idx_ws[row];
        float4 q = ((const float4*)(E + (size_t)k * DIM))[lane];
        float4 x = ((const float4*)(X + (size_t)row * DIM))[lane];
        ((float4*)(out + (size_t)row * DIM))[lane] = q;
        double d0 = (double)q.x - (double)x.x;
        double d1 = (double)q.y - (double)x.y;
        double d2 = (double)q.z - (double)x.z;
        double d3 = (double)q.w - (double)x.w;
        ls += d0 * d0 + d1 * d1 + d2 * d2 + d3 * d3;
        if (lane == 0) {
            atomicAdd(&counts[k], 1);
            out[OUT_IDX + row] = (float)k;
        }
    }
    __shared__ double red[256];
    red[tid] = ls;
    __syncthreads();
    for (int s = 128; s > 0; s >>= 1) {
        if (tid < s) red[tid] += red[tid + s];
        __syncthreads();
    }
    if (tid == 0) atomicAdd(loss, red[0]);
}

// ---------------------------------------------------------------------------
// fin: scalars
__global__ void k_fin(const int* __restrict__ counts, const double* __restrict__ loss,
                      float* __restrict__ out) {
    int t = threadIdx.x;
    __shared__ double red[256];
    double h = 0.0;
    #pragma unroll
    for (int i = 0; i < 4; ++i) {
        double p = (double)counts[t + i * 256] / (double)N_ROWS;
        h += p * log(p + 1e-10);
    }
    red[t] = h;
    __syncthreads();
    for (int s = 128; s > 0; s >>= 1) {
        if (t < s) red[t] += red[t + s];
        __syncthreads();
    }
    if (t == 0) {
        out[OUT_PERP] = (float)exp(-red[0]);
        out[OUT_LOSS] = (float)((*loss) / (double)Q_SIZE * 1.25);
    }
}

// ---------------------------------------------------------------------------
extern "C" void kernel_launch(void* const* d_in, const int* in_sizes, int n_in,
                              void* d_out, int out_size, void* d_ws, size_t ws_size,
                              hipStream_t stream) {
    (void)in_sizes; (void)n_in; (void)out_size; (void)ws_size;
    const float* X = (const float*)d_in[0];
    const float* E = (const float*)d_in[1];
    float* out = (float*)d_out;
    char* ws = (char*)d_ws;

    double*    loss   = (double*)(ws + WS_LOSS);
    int*       rcnt   = (int*)(ws + WS_RCNT);
    float*     e2     = (float*)(ws + WS_E2);
    float*     e2p    = (float*)(ws + WS_E2P);
    int*       counts = (int*)(ws + WS_COUNTS);
    int*       idx_ws = (int*)(ws + WS_IDX);
    int*       rlist  = (int*)(ws + WS_RLIST);
    float*     Et     = (float*)(ws + WS_ET);
    _Float16*  Pp     = (_Float16*)(ws + WS_P);

    k_prep<<<1024, 256, 0, stream>>>(E, e2, e2p, Et, Pp, counts, loss, rcnt);
    k_main<<<N_ROWS / RPB, 256, 0, stream>>>(X, Pp, e2p, idx_ws, rlist, rcnt);
    k_refine<<<1024, 256, 0, stream>>>(X, Et, e2, rlist, rcnt, idx_ws);
    k_out<<<1024, 256, 0, stream>>>(X, E, idx_ws, out, counts, loss);
    k_fin<<<1, 256, 0, stream>>>(counts, loss, out);
}